// Round 6
// baseline (176.322 us; speedup 1.0000x reference)
//
#include <hip/hip_runtime.h>
#include <hip/hip_bf16.h>

// AffineLayer2d: 256 3x3 expm -> affine grid -> bilinear sample.
// x[8,3,224,224] f32, ksamp[6,8,32] f32, rf[6] f32 -> out[8,32,3,224,224] f32.
//
// Ladder: R1 naive 120us (TA-bound, 12 scalar gathers). R2 NHWC-pad4 float4
// ~43us. R4 4px/thread regressed (VGPR pressure). R5 bf16x4 8B/px ~38us --
// but 16B memcpy from 8-aligned ptr still emitted 4 scattered dwordx2/px.
// R6: SELF+NEXT replicated bf16 layout, 16B/px record = (c01[x],c2[x],
// c01[x+1],c2[x+1]), 16-aligned -> ONE dwordx4 per source row = 2 scattered
// gathers/px (was 4). Edge cases via 2 cndmask selects. NT stores keep the
// 154MB out stream from evicting the 6.4MB L2-resident xi.
// Fixed, uncontrollable: ~122us of harness poison fills inside the timed graph.

#define PI_F 3.14159265358979323846f

typedef uint uvec4 __attribute__((ext_vector_type(4)));

constexpr int N_ = 8, C_ = 3, H_ = 224, W_ = 224, S_ = 32;
constexpr int HW_ = H_ * W_;              // 50176
constexpr int B_ = N_ * S_;               // 256 transforms
constexpr int BLOCKS_PER_IMG = HW_ / 256; // 196

constexpr size_t THETA_OFF = 0;
constexpr size_t XI_OFF    = 8192;        // self+next bf16 image, 6.4 MB

// bf16 pair unpack: u holds (lo16=bf16 a, hi16=bf16 b)
__device__ inline float bflo(uint u) { return __uint_as_float(u << 16); }
__device__ inline float bfhi(uint u) { return __uint_as_float(u & 0xffff0000u); }

// ---------------- Stage 1: theta = expm(M)[:, :2, :] ----------------
__device__ void compute_theta(const float* __restrict__ ksamp,
                              const float* __restrict__ rf,
                              float* __restrict__ theta) {
    int t = threadIdx.x;  // 256 threads = 256 transforms
    int n = t / S_, s = t % S_;

    float kk[6];
#pragma unroll
    for (int j = 0; j < 6; ++j)
        kk[j] = ksamp[j * (N_ * S_) + n * S_ + s] * 2.f - 1.f;

    float c2 = fminf(fmaxf(rf[2], -PI_F), PI_F);
    float a = kk[0] * rf[0];
    float b = kk[1] * rf[1];
    float r = kk[2] * c2;
    float d = kk[3] * rf[3];
    float e = kk[4] * rf[4];
    float f = kk[5] * rf[5];

    float A[9] = { d,     f - r, a,
                   f + r, e,     b,
                   0.f,   0.f,   0.f };

#pragma unroll
    for (int i = 0; i < 9; ++i) A[i] *= (1.f / 64.f);

    float out[9] = {1,0,0, 0,1,0, 0,0,1};
#pragma unroll
    for (int i = 0; i < 9; ++i) out[i] += A[i];

    float term[9];
#pragma unroll
    for (int i = 0; i < 9; ++i) term[i] = A[i];

#pragma unroll
    for (int it = 2; it <= 12; ++it) {
        float inv = 1.f / (float)it;
        float nt[9];
#pragma unroll
        for (int rr = 0; rr < 3; ++rr)
#pragma unroll
            for (int cc = 0; cc < 3; ++cc)
                nt[rr*3+cc] = (term[rr*3+0]*A[0*3+cc] +
                               term[rr*3+1]*A[1*3+cc] +
                               term[rr*3+2]*A[2*3+cc]) * inv;
#pragma unroll
        for (int i = 0; i < 9; ++i) { term[i] = nt[i]; out[i] += nt[i]; }
    }
#pragma unroll
    for (int sq = 0; sq < 6; ++sq) {
        float nt[9];
#pragma unroll
        for (int rr = 0; rr < 3; ++rr)
#pragma unroll
            for (int cc = 0; cc < 3; ++cc)
                nt[rr*3+cc] = out[rr*3+0]*out[0*3+cc] +
                              out[rr*3+1]*out[1*3+cc] +
                              out[rr*3+2]*out[2*3+cc];
#pragma unroll
        for (int i = 0; i < 9; ++i) out[i] = nt[i];
    }

    theta[t*6+0] = out[0]; theta[t*6+1] = out[1]; theta[t*6+2] = out[2];
    theta[t*6+3] = out[3]; theta[t*6+4] = out[4]; theta[t*6+5] = out[5];
}

// NCHW fp32 -> self+next bf16 records (16B/px). Coalesced reads (neighbor
// reads are L1 hits) + coalesced dwordx4 stores.
__global__ __launch_bounds__(256) void prep_kernel(const float* __restrict__ x,
                                                   const float* __restrict__ ksamp,
                                                   const float* __restrict__ rf,
                                                   uvec4* __restrict__ xi,
                                                   float* __restrict__ theta) {
    int idx = blockIdx.x * 256 + threadIdx.x;   // over N*HW
    int n = idx / HW_, p = idx - n * HW_;
    int h = p / W_, w = p - h * W_;
    int pn = (w == W_ - 1) ? p : p + 1;         // next px in row, clamped

    const float* base = x + n * (C_ * HW_);
    uint b0 = (uint)__bfloat16_as_ushort(__float2bfloat16(base[p]));
    uint b1 = (uint)__bfloat16_as_ushort(__float2bfloat16(base[HW_ + p]));
    uint b2 = (uint)__bfloat16_as_ushort(__float2bfloat16(base[2 * HW_ + p]));
    uint n0 = (uint)__bfloat16_as_ushort(__float2bfloat16(base[pn]));
    uint n1 = (uint)__bfloat16_as_ushort(__float2bfloat16(base[HW_ + pn]));
    uint n2 = (uint)__bfloat16_as_ushort(__float2bfloat16(base[2 * HW_ + pn]));

    uvec4 v;
    v.x = b0 | (b1 << 16);   // c0,c1 of px
    v.y = b2;                // c2 of px
    v.z = n0 | (n1 << 16);   // c0,c1 of px+1
    v.w = n2;                // c2 of px+1
    xi[idx] = v;

    if (blockIdx.x == 0) compute_theta(ksamp, rf, theta);
}

// ---------------- Stage 2: affine grid + bilinear sample, 1 px/thread ----------------
__global__ __launch_bounds__(256) void sample_kernel(const uvec4* __restrict__ xi,
                                                     const float* __restrict__ theta,
                                                     float* __restrict__ out) {
    int blk = blockIdx.x;
    int b   = blk / BLOCKS_PER_IMG;                    // uniform per block
    int pix = (blk % BLOCKS_PER_IMG) * 256 + threadIdx.x;
    int h = pix / W_, w = pix - h * W_;
    int n = b / S_;

    const float* th = theta + b * 6;
    float t00 = th[0], t01 = th[1], t02 = th[2];
    float t10 = th[3], t11 = th[4], t12 = th[5];

    float gx = fmaf((float)w, 2.f / (W_ - 1), -1.f);
    float gy = fmaf((float)h, 2.f / (H_ - 1), -1.f);

    float gridx = t00 * gx + t01 * gy + t02;
    float gridy = t10 * gx + t11 * gy + t12;

    float ix = (gridx + 1.f) * (0.5f * (W_ - 1));
    float iy = (gridy + 1.f) * (0.5f * (H_ - 1));

    float x0f = floorf(ix), y0f = floorf(iy);
    float wx1 = ix - x0f, wx0 = 1.f - wx1;
    float wy1 = iy - y0f, wy0 = 1.f - wy1;

    int x0 = (int)x0f, y0 = (int)y0f;
    int x1 = x0 + 1,   y1 = y0 + 1;

    bool vx0 = (x0 >= 0) && (x0 <= W_ - 1);
    bool vx1 = (x1 >= 0) && (x1 <= W_ - 1);
    bool vy0 = (y0 >= 0) && (y0 <= H_ - 1);
    bool vy1 = (y1 >= 0) && (y1 <= H_ - 1);

    float w00 = (vy0 && vx0) ? wy0 * wx0 : 0.f;
    float w01 = (vy0 && vx1) ? wy0 * wx1 : 0.f;
    float w10 = (vy1 && vx0) ? wy1 * wx0 : 0.f;
    float w11 = (vy1 && vx1) ? wy1 * wx1 : 0.f;

    int y0c = min(max(y0, 0), H_ - 1), y1c = min(max(y1, 0), H_ - 1);
    int xl  = min(max(x0, 0), W_ - 2);         // record at xl covers px xl, xl+1

    const uvec4* img = xi + n * HW_;
    uvec4 r0 = img[y0c * W_ + xl];             // single 16B aligned dwordx4
    uvec4 r1 = img[y1c * W_ + xl];

    // val0 (weight w00/w10) is normally lo half; hi half only when x0 == W-1.
    // val1 (weight w01/w11) is normally hi half; lo half only when x0 < 0.
    bool hi0 = (x0 > xl);    // x0 == W-1
    bool lo1 = (x0 < xl);    // x0 < 0

    uint a01 = hi0 ? r0.z : r0.x;  uint a2 = hi0 ? r0.w : r0.y;  // p00
    uint b01 = lo1 ? r0.x : r0.z;  uint b2 = lo1 ? r0.y : r0.w;  // p01
    uint c01 = hi0 ? r1.z : r1.x;  uint c2 = hi0 ? r1.w : r1.y;  // p10
    uint d01 = lo1 ? r1.x : r1.z;  uint d2 = lo1 ? r1.y : r1.w;  // p11

    float vx = w00 * bflo(a01) + w01 * bflo(b01) + w10 * bflo(c01) + w11 * bflo(d01);
    float vy = w00 * bfhi(a01) + w01 * bfhi(b01) + w10 * bfhi(c01) + w11 * bfhi(d01);
    float vz = w00 * bflo(a2)  + w01 * bflo(b2)  + w10 * bflo(c2)  + w11 * bflo(d2);

    float* ob = out + (size_t)b * (C_ * HW_) + pix;
    __builtin_nontemporal_store(vx, ob);
    __builtin_nontemporal_store(vy, ob + HW_);
    __builtin_nontemporal_store(vz, ob + 2 * (size_t)HW_);
}

extern "C" void kernel_launch(void* const* d_in, const int* in_sizes, int n_in,
                              void* d_out, int out_size, void* d_ws, size_t ws_size,
                              hipStream_t stream) {
    const float* x     = (const float*)d_in[0];
    const float* ksamp = (const float*)d_in[1];
    const float* rf    = (const float*)d_in[2];
    float* out   = (float*)d_out;
    float* theta = (float*)((char*)d_ws + THETA_OFF);
    uvec4* xi    = (uvec4*)((char*)d_ws + XI_OFF);

    prep_kernel<<<N_ * BLOCKS_PER_IMG, 256, 0, stream>>>(x, ksamp, rf, xi, theta);
    sample_kernel<<<B_ * BLOCKS_PER_IMG, 256, 0, stream>>>(xi, theta, out);
}